// Round 5
// baseline (833.990 us; speedup 1.0000x reference)
//
#include <hip/hip_runtime.h>
#include <hip/hip_bf16.h>

#define I_DIM  512
#define O_DIM  512
#define NBATCH 1024
#define NSPL   8            // spline coeffs per input channel
#define KPI    12           // K slots per channel: 8 spline + s_hi,s_hi,s_lo,0
#define KDIM   (I_DIM * KPI)   // 6144
#define NGRID  12           // extended grid points per channel
#define SPLITK 16
#define NBLK   512          // 2 blocks/CU: co-resident by construction
#define NTHR   256
#define NTOT   (NBLK * NTHR)   // 131072 threads

typedef __attribute__((ext_vector_type(8))) short bf16x8;
typedef __attribute__((ext_vector_type(4))) float f32x4;

// async global->LDS 16B: per-lane source, wave-uniform LDS base (+lane*16 in HW)
__device__ __forceinline__ void gload_lds16(const __hip_bfloat16* g, __hip_bfloat16* l) {
    __builtin_amdgcn_global_load_lds(
        (const __attribute__((address_space(1))) void*)g,
        (__attribute__((address_space(3))) void*)l, 16, 0, 0);
}

// ---------------------------------------------------------------------------
// Manual grid barrier: one-shot arrival counters (zeroed by hipMemsetAsync
// before launch), 128B apart. Deadlock-safe because all NBLK blocks are
// co-resident (2/CU, enforced by __launch_bounds__(256,2) + 32KB LDS).
// ---------------------------------------------------------------------------
__device__ __forceinline__ void grid_barrier(int* bar, int phase) {
    __syncthreads();
    if (threadIdx.x == 0) {
        int* c = bar + phase * 32;   // 128 B per phase counter
        __threadfence();             // agent-scope release of prior writes
        __hip_atomic_fetch_add(c, 1, __ATOMIC_ACQ_REL, __HIP_MEMORY_SCOPE_AGENT);
        while (__hip_atomic_load(c, __ATOMIC_ACQUIRE, __HIP_MEMORY_SCOPE_AGENT) < NBLK)
            __builtin_amdgcn_s_sleep(8);
        __threadfence();             // acquire: invalidate stale cached data
    }
    __syncthreads();
}

// ---------------------------------------------------------------------------
// Wt row: slots 0..7 = sp*coef[k]; 8=hi(sb); 9=lo(sb); 10=hi(sb); 11=0.
// Pairs with features [B0..B7, s_hi, s_hi, s_lo, 0]:
//   s_hi*w_hi + s_hi*w_lo + s_lo*w_hi ~= s*sb  (rel err ~2^-17; verified r1-r3)
// ---------------------------------------------------------------------------
__device__ __forceinline__ void wt_core(const float* __restrict__ coef,
                                        const float* __restrict__ sb,
                                        const float* __restrict__ sp,
                                        __hip_bfloat16* __restrict__ W, int tid) {
    int i = tid & (I_DIM - 1);
    int o = tid >> 9;
    float sbv = sb[i * O_DIM + o];
    float spv = sp[i * O_DIM + o];
    const float* cf = coef + (size_t)(i * O_DIM + o) * NSPL;
    __align__(16) __hip_bfloat16 row[KPI];
#pragma unroll
    for (int k = 0; k < NSPL; ++k) row[k] = __float2bfloat16(spv * cf[k]);
    __hip_bfloat16 whi = __float2bfloat16(sbv);
    __hip_bfloat16 wlo = __float2bfloat16(sbv - __bfloat162float(whi));
    row[8]  = whi;
    row[9]  = wlo;
    row[10] = whi;
    row[11] = __float2bfloat16(0.0f);
    uint2* dst = (uint2*)(W + (size_t)o * KDIM + i * KPI);
    const uint2* src = (const uint2*)row;
    dst[0] = src[0]; dst[1] = src[1]; dst[2] = src[2];
}

__device__ __forceinline__ void features_core(float xv, const float* __restrict__ grid,
                                              int i, __hip_bfloat16* __restrict__ dst) {
    float g[NGRID];
#pragma unroll
    for (int j = 0; j < NGRID; ++j) g[j] = grid[i * NGRID + j];

    float B[NGRID - 1];
#pragma unroll
    for (int j = 0; j < NGRID - 1; ++j)
        B[j] = (xv >= g[j] && xv < g[j + 1]) ? 1.0f : 0.0f;
#pragma unroll
    for (int p = 1; p <= 3; ++p) {
#pragma unroll
        for (int j = 0; j < NGRID - 1 - p; ++j) {
            B[j] = (xv - g[j]) / (g[j + p] - g[j]) * B[j]
                 + (g[j + p + 1] - xv) / (g[j + p + 1] - g[j + 1]) * B[j + 1];
        }
    }
    float s = xv / (1.0f + __expf(-xv));  // silu
    __hip_bfloat16 shi = __float2bfloat16(s);
    __hip_bfloat16 slo = __float2bfloat16(s - __bfloat162float(shi));

    __align__(16) __hip_bfloat16 row[KPI];
#pragma unroll
    for (int k = 0; k < NSPL; ++k) row[k] = __float2bfloat16(B[k]);
    row[8]  = shi;
    row[9]  = shi;
    row[10] = slo;
    row[11] = __float2bfloat16(0.0f);

    uint2* d = (uint2*)dst;
    const uint2* srow = (const uint2*)row;
    d[0] = srow[0]; d[1] = srow[1]; d[2] = srow[2];
}

// ---------------------------------------------------------------------------
// GEMM stage (numerics verified r2/r3): 128x128 tile, BK=64, 4 waves x 64x64
// quadrant (4x4 MFMA), global_load_lds w16, XOR-swizzled LDS chunks, splitK=16.
// blk = bm + 8*bn + 32*ks  (512 blocks exactly).
// ---------------------------------------------------------------------------
#define BM 128
#define BN 128
#define BK 64
#define KSEG (KDIM / SPLITK)   // 384 -> 6 K-rounds

__device__ __forceinline__ void gemm_stage(const __hip_bfloat16* __restrict__ A,
                                           const __hip_bfloat16* __restrict__ Wt,
                                           float* __restrict__ P,
                                           __hip_bfloat16* lA, __hip_bfloat16* lB,
                                           int blk, int tid) {
    int bm = blk & 7;
    int bn = (blk >> 3) & 3;
    int ks = blk >> 5;
    int lane = tid & 63;
    int wave = tid >> 6;
    int wr = (wave & 1) * 64;
    int wc = (wave >> 1) * 64;
    int q  = lane >> 4;
    int ln = lane & 15;

    f32x4 acc[4][4];
#pragma unroll
    for (int a = 0; a < 4; ++a)
#pragma unroll
        for (int b = 0; b < 4; ++b) acc[a][b] = (f32x4){0.f, 0.f, 0.f, 0.f};

    const __hip_bfloat16* Abase = A  + (size_t)(bm * BM) * KDIM + ks * KSEG;
    const __hip_bfloat16* Bbase = Wt + (size_t)(bn * BN) * KDIM + ks * KSEG;

    int ccw[4], rr[4], jj[4];
#pragma unroll
    for (int c = 0; c < 4; ++c) {
        int cc = c * 256 + tid;
        ccw[c] = c * 256 + wave * 64;
        rr[c] = cc >> 3;
        jj[c] = (cc & 7) ^ (rr[c] & 7);
    }

    for (int kt = 0; kt < KSEG; kt += BK) {
        __syncthreads();
#pragma unroll
        for (int c = 0; c < 4; ++c)
            gload_lds16(Abase + (size_t)rr[c] * KDIM + kt + jj[c] * 8, lA + ccw[c] * 8);
#pragma unroll
        for (int c = 0; c < 4; ++c)
            gload_lds16(Bbase + (size_t)rr[c] * KDIM + kt + jj[c] * 8, lB + ccw[c] * 8);
        __syncthreads();

#pragma unroll
        for (int kh = 0; kh < 2; ++kh) {
            bf16x8 af[4], bf[4];
#pragma unroll
            for (int rt = 0; rt < 4; ++rt) {
                int row = wr + rt * 16 + ln;
                af[rt] = *(const bf16x8*)(lA + row * BK + (((kh * 4 + q) ^ (row & 7)) * 8));
            }
#pragma unroll
            for (int ct = 0; ct < 4; ++ct) {
                int row = wc + ct * 16 + ln;
                bf[ct] = *(const bf16x8*)(lB + row * BK + (((kh * 4 + q) ^ (row & 7)) * 8));
            }
#pragma unroll
            for (int rt = 0; rt < 4; ++rt)
#pragma unroll
                for (int ct = 0; ct < 4; ++ct)
                    acc[rt][ct] = __builtin_amdgcn_mfma_f32_16x16x32_bf16(
                        af[rt], bf[ct], acc[rt][ct], 0, 0, 0);
        }
    }

    float* Pp = P + (size_t)ks * NBATCH * O_DIM;
    int orow = bm * BM + wr;
    int ocol = bn * BN + wc + ln;
#pragma unroll
    for (int rt = 0; rt < 4; ++rt)
#pragma unroll
        for (int ct = 0; ct < 4; ++ct)
#pragma unroll
            for (int r = 0; r < 4; ++r)
                Pp[(size_t)(orow + rt * 16 + q * 4 + r) * O_DIM + ocol + ct * 16]
                    = acc[rt][ct][r];
}

// ---------------------------------------------------------------------------
// Single persistent kernel: prep -> [gemm -> features]x3 -> reduce,
// manual grid barriers (6 phases).
// ---------------------------------------------------------------------------
__global__ __launch_bounds__(NTHR, 2)
void fused_kan(const float* __restrict__ x0,
               const float* __restrict__ g0, const float* __restrict__ c0,
               const float* __restrict__ b0, const float* __restrict__ p0,
               const float* __restrict__ g1, const float* __restrict__ c1,
               const float* __restrict__ b1, const float* __restrict__ p1,
               const float* __restrict__ g2, const float* __restrict__ c2,
               const float* __restrict__ b2, const float* __restrict__ p2,
               __hip_bfloat16* __restrict__ Wt, __hip_bfloat16* __restrict__ F,
               float* __restrict__ P, int* __restrict__ bar,
               float* __restrict__ out) {
    __shared__ __hip_bfloat16 lA[BM * BK];   // 16 KB
    __shared__ __hip_bfloat16 lB[BN * BK];   // 16 KB

    int blk = blockIdx.x;
    int tid = threadIdx.x;
    int gtid = blk * NTHR + tid;

    // ---- prep: Wt for 3 layers (786432 items = 6 iters) ----
#pragma unroll
    for (int it = 0; it < 6; ++it) {
        int idx = it * NTOT + gtid;
        int l = idx >> 18;                       // 262144 items per layer
        const float* coef = l == 0 ? c0 : (l == 1 ? c1 : c2);
        const float* sb   = l == 0 ? b0 : (l == 1 ? b1 : b2);
        const float* sp   = l == 0 ? p0 : (l == 1 ? p1 : p2);
        wt_core(coef, sb, sp, Wt + (size_t)l * O_DIM * KDIM, idx & 262143);
    }
    // ---- features layer 0 (524288 items = 4 iters) ----
#pragma unroll
    for (int it = 0; it < 4; ++it) {
        int idx = it * NTOT + gtid;
        features_core(x0[idx], g0, idx & (I_DIM - 1), F + (size_t)idx * KPI);
    }
    grid_barrier(bar, 0);

    int phase = 1;
    for (int l = 0; l < 3; ++l) {
        gemm_stage(F, Wt + (size_t)l * O_DIM * KDIM, P, lA, lB, blk, tid);
        grid_barrier(bar, phase++);
        if (l < 2) {
            const float* gr = (l == 0) ? g1 : g2;
#pragma unroll
            for (int it = 0; it < 4; ++it) {
                int idx = it * NTOT + gtid;
                float xv = 0.f;
#pragma unroll
                for (int s = 0; s < SPLITK; ++s)
                    xv += P[(size_t)s * (NBATCH * I_DIM) + idx];
                features_core(xv, gr, idx & (I_DIM - 1), F + (size_t)idx * KPI);
            }
            grid_barrier(bar, phase++);
        }
    }

    // ---- final splitK reduce -> out ----
#pragma unroll
    for (int it = 0; it < 4; ++it) {
        int idx = it * NTOT + gtid;
        float v = 0.f;
#pragma unroll
        for (int s = 0; s < SPLITK; ++s)
            v += P[(size_t)s * (NBATCH * O_DIM) + idx];
        out[idx] = v;
    }
}

// ---------------------------------------------------------------------------
extern "C" void kernel_launch(void* const* d_in, const int* in_sizes, int n_in,
                              void* d_out, int out_size, void* d_ws, size_t ws_size,
                              hipStream_t stream) {
    const float* x0 = (const float*)d_in[0];
    const float* g0 = (const float*)d_in[1];
    const float* c0 = (const float*)d_in[2];
    const float* b0 = (const float*)d_in[3];
    const float* p0 = (const float*)d_in[4];
    const float* g1 = (const float*)d_in[5];
    const float* c1 = (const float*)d_in[6];
    const float* b1 = (const float*)d_in[7];
    const float* p1 = (const float*)d_in[8];
    const float* g2 = (const float*)d_in[9];
    const float* c2 = (const float*)d_in[10];
    const float* b2 = (const float*)d_in[11];
    const float* p2 = (const float*)d_in[12];

    char* ws = (char*)d_ws;
    const size_t wt_bytes = (size_t)O_DIM * KDIM * sizeof(__hip_bfloat16);   // 6.3 MB/layer
    const size_t f_bytes  = (size_t)NBATCH * KDIM * sizeof(__hip_bfloat16);  // 12.6 MB
    __hip_bfloat16* Wt = (__hip_bfloat16*)ws;
    __hip_bfloat16* F  = (__hip_bfloat16*)(ws + 3 * wt_bytes);
    float* P  = (float*)(ws + 3 * wt_bytes + f_bytes);   // [16][1024][512] fp32 = 33.6 MB
    int* bar  = (int*)(ws + (size_t)128 * 1024 * 1024);  // barrier counters, far from data
    float* out = (float*)d_out;

    // zero the 6 one-shot barrier counters (6 * 128 B); capture-legal memset node
    hipMemsetAsync(bar, 0, 4096, stream);

    fused_kan<<<NBLK, NTHR, 0, stream>>>(
        x0, g0, c0, b0, p0, g1, c1, b1, p1, g2, c2, b2, p2,
        Wt, F, P, bar, out);
}

// Round 6
// 607.516 us; speedup vs baseline: 1.3728x; 1.3728x over previous
//
#include <hip/hip_runtime.h>
#include <hip/hip_bf16.h>

#define I_DIM  512
#define O_DIM  512
#define NBATCH 1024
#define NSPL   8            // spline coeffs per input channel
#define KPI    12           // K slots per channel: 8 spline + s_hi,s_hi,s_lo,0
#define KDIM   (I_DIM * KPI)   // 6144
#define NGRID  12           // extended grid points per channel
#define SPLITK 16
#define NBLK   512          // 2 blocks/CU: co-resident by construction
#define NTHR   256
#define NTOT   (NBLK * NTHR)   // 131072 threads

typedef __attribute__((ext_vector_type(8))) short bf16x8;
typedef __attribute__((ext_vector_type(4))) float f32x4;

// async global->LDS 16B: per-lane source, wave-uniform LDS base (+lane*16 in HW)
__device__ __forceinline__ void gload_lds16(const __hip_bfloat16* g, __hip_bfloat16* l) {
    __builtin_amdgcn_global_load_lds(
        (const __attribute__((address_space(1))) void*)g,
        (__attribute__((address_space(3))) void*)l, 16, 0, 0);
}

// ---------------------------------------------------------------------------
// Manual grid barrier, one-shot counters (zeroed by hipMemsetAsync pre-launch).
// r5 lesson: ACQUIRE polls emit buffer_inv per iteration -> continuous L2
// invalidation across XCDs -> 341MB refetch, 720us. Fix: RELEASE add once,
// RELAXED polls (coherent-point read, no invalidation), then exactly ONE
// ACQUIRE load after the trip to invalidate stale lines before consuming.
// Deadlock-safe: 512 blocks = 2/CU co-resident (launch_bounds(256,2), 32KB LDS).
// ---------------------------------------------------------------------------
__device__ __forceinline__ void grid_barrier(int* bar, int phase) {
    __syncthreads();
    if (threadIdx.x == 0) {
        int* c = bar + phase * 32;   // 128 B per phase counter
        __hip_atomic_fetch_add(c, 1, __ATOMIC_RELEASE, __HIP_MEMORY_SCOPE_AGENT);
        while (__hip_atomic_load(c, __ATOMIC_RELAXED, __HIP_MEMORY_SCOPE_AGENT) < NBLK)
            __builtin_amdgcn_s_sleep(16);
        (void)__hip_atomic_load(c, __ATOMIC_ACQUIRE, __HIP_MEMORY_SCOPE_AGENT);
    }
    __syncthreads();
}

// ---------------------------------------------------------------------------
// Wt row: slots 0..7 = sp*coef[k]; 8=hi(sb); 9=lo(sb); 10=hi(sb); 11=0.
// Pairs with features [B0..B7, s_hi, s_hi, s_lo, 0]:
//   s_hi*w_hi + s_hi*w_lo + s_lo*w_hi ~= s*sb  (rel err ~2^-17; verified r1-r5)
// ---------------------------------------------------------------------------
__device__ __forceinline__ void wt_core(const float* __restrict__ coef,
                                        const float* __restrict__ sb,
                                        const float* __restrict__ sp,
                                        __hip_bfloat16* __restrict__ W, int tid) {
    int i = tid & (I_DIM - 1);
    int o = tid >> 9;
    float sbv = sb[i * O_DIM + o];
    float spv = sp[i * O_DIM + o];
    const float* cf = coef + (size_t)(i * O_DIM + o) * NSPL;
    __align__(16) __hip_bfloat16 row[KPI];
#pragma unroll
    for (int k = 0; k < NSPL; ++k) row[k] = __float2bfloat16(spv * cf[k]);
    __hip_bfloat16 whi = __float2bfloat16(sbv);
    __hip_bfloat16 wlo = __float2bfloat16(sbv - __bfloat162float(whi));
    row[8]  = whi;
    row[9]  = wlo;
    row[10] = whi;
    row[11] = __float2bfloat16(0.0f);
    uint2* dst = (uint2*)(W + (size_t)o * KDIM + i * KPI);
    const uint2* src = (const uint2*)row;
    dst[0] = src[0]; dst[1] = src[1]; dst[2] = src[2];
}

__device__ __forceinline__ void features_core(float xv, const float* __restrict__ grid,
                                              int i, __hip_bfloat16* __restrict__ dst) {
    float g[NGRID];
#pragma unroll
    for (int j = 0; j < NGRID; ++j) g[j] = grid[i * NGRID + j];

    float B[NGRID - 1];
#pragma unroll
    for (int j = 0; j < NGRID - 1; ++j)
        B[j] = (xv >= g[j] && xv < g[j + 1]) ? 1.0f : 0.0f;
#pragma unroll
    for (int p = 1; p <= 3; ++p) {
#pragma unroll
        for (int j = 0; j < NGRID - 1 - p; ++j) {
            B[j] = (xv - g[j]) / (g[j + p] - g[j]) * B[j]
                 + (g[j + p + 1] - xv) / (g[j + p + 1] - g[j + 1]) * B[j + 1];
        }
    }
    float s = xv / (1.0f + __expf(-xv));  // silu
    __hip_bfloat16 shi = __float2bfloat16(s);
    __hip_bfloat16 slo = __float2bfloat16(s - __bfloat162float(shi));

    __align__(16) __hip_bfloat16 row[KPI];
#pragma unroll
    for (int k = 0; k < NSPL; ++k) row[k] = __float2bfloat16(B[k]);
    row[8]  = shi;
    row[9]  = shi;
    row[10] = slo;
    row[11] = __float2bfloat16(0.0f);

    uint2* d = (uint2*)dst;
    const uint2* srow = (const uint2*)row;
    d[0] = srow[0]; d[1] = srow[1]; d[2] = srow[2];
}

// ---------------------------------------------------------------------------
// GEMM stage (numerics verified r2-r5): 128x128 tile, BK=64, 4 waves x 64x64
// quadrant (4x4 MFMA), global_load_lds w16, XOR-swizzled LDS chunks, splitK=16.
// blk = bm + 8*bn + 32*ks  (512 blocks exactly).
// ---------------------------------------------------------------------------
#define BM 128
#define BN 128
#define BK 64
#define KSEG (KDIM / SPLITK)   // 384 -> 6 K-rounds

__device__ __forceinline__ void gemm_stage(const __hip_bfloat16* __restrict__ A,
                                           const __hip_bfloat16* __restrict__ Wt,
                                           float* __restrict__ P,
                                           __hip_bfloat16* lA, __hip_bfloat16* lB,
                                           int blk, int tid) {
    int bm = blk & 7;
    int bn = (blk >> 3) & 3;
    int ks = blk >> 5;
    int lane = tid & 63;
    int wave = tid >> 6;
    int wr = (wave & 1) * 64;
    int wc = (wave >> 1) * 64;
    int q  = lane >> 4;
    int ln = lane & 15;

    f32x4 acc[4][4];
#pragma unroll
    for (int a = 0; a < 4; ++a)
#pragma unroll
        for (int b = 0; b < 4; ++b) acc[a][b] = (f32x4){0.f, 0.f, 0.f, 0.f};

    const __hip_bfloat16* Abase = A  + (size_t)(bm * BM) * KDIM + ks * KSEG;
    const __hip_bfloat16* Bbase = Wt + (size_t)(bn * BN) * KDIM + ks * KSEG;

    int ccw[4], rr[4], jj[4];
#pragma unroll
    for (int c = 0; c < 4; ++c) {
        int cc = c * 256 + tid;
        ccw[c] = c * 256 + wave * 64;
        rr[c] = cc >> 3;
        jj[c] = (cc & 7) ^ (rr[c] & 7);
    }

    for (int kt = 0; kt < KSEG; kt += BK) {
        __syncthreads();
#pragma unroll
        for (int c = 0; c < 4; ++c)
            gload_lds16(Abase + (size_t)rr[c] * KDIM + kt + jj[c] * 8, lA + ccw[c] * 8);
#pragma unroll
        for (int c = 0; c < 4; ++c)
            gload_lds16(Bbase + (size_t)rr[c] * KDIM + kt + jj[c] * 8, lB + ccw[c] * 8);
        __syncthreads();

#pragma unroll
        for (int kh = 0; kh < 2; ++kh) {
            bf16x8 af[4], bf[4];
#pragma unroll
            for (int rt = 0; rt < 4; ++rt) {
                int row = wr + rt * 16 + ln;
                af[rt] = *(const bf16x8*)(lA + row * BK + (((kh * 4 + q) ^ (row & 7)) * 8));
            }
#pragma unroll
            for (int ct = 0; ct < 4; ++ct) {
                int row = wc + ct * 16 + ln;
                bf[ct] = *(const bf16x8*)(lB + row * BK + (((kh * 4 + q) ^ (row & 7)) * 8));
            }
#pragma unroll
            for (int rt = 0; rt < 4; ++rt)
#pragma unroll
                for (int ct = 0; ct < 4; ++ct)
                    acc[rt][ct] = __builtin_amdgcn_mfma_f32_16x16x32_bf16(
                        af[rt], bf[ct], acc[rt][ct], 0, 0, 0);
        }
    }

    float* Pp = P + (size_t)ks * NBATCH * O_DIM;
    int orow = bm * BM + wr;
    int ocol = bn * BN + wc + ln;
#pragma unroll
    for (int rt = 0; rt < 4; ++rt)
#pragma unroll
        for (int ct = 0; ct < 4; ++ct)
#pragma unroll
            for (int r = 0; r < 4; ++r)
                Pp[(size_t)(orow + rt * 16 + q * 4 + r) * O_DIM + ocol + ct * 16]
                    = acc[rt][ct][r];
}

// ---------------------------------------------------------------------------
// Single persistent kernel: prep -> [gemm -> features]x3 -> reduce,
// manual grid barriers (6 phases).
// ---------------------------------------------------------------------------
__global__ __launch_bounds__(NTHR, 2)
void fused_kan(const float* __restrict__ x0,
               const float* __restrict__ g0, const float* __restrict__ c0,
               const float* __restrict__ b0, const float* __restrict__ p0,
               const float* __restrict__ g1, const float* __restrict__ c1,
               const float* __restrict__ b1, const float* __restrict__ p1,
               const float* __restrict__ g2, const float* __restrict__ c2,
               const float* __restrict__ b2, const float* __restrict__ p2,
               __hip_bfloat16* __restrict__ Wt, __hip_bfloat16* __restrict__ F,
               float* __restrict__ P, int* __restrict__ bar,
               float* __restrict__ out) {
    __shared__ __hip_bfloat16 lA[BM * BK];   // 16 KB
    __shared__ __hip_bfloat16 lB[BN * BK];   // 16 KB

    int blk = blockIdx.x;
    int tid = threadIdx.x;
    int gtid = blk * NTHR + tid;

    // ---- prep: Wt for 3 layers (786432 items = 6 iters) ----
#pragma unroll
    for (int it = 0; it < 6; ++it) {
        int idx = it * NTOT + gtid;
        int l = idx >> 18;                       // 262144 items per layer
        const float* coef = l == 0 ? c0 : (l == 1 ? c1 : c2);
        const float* sb   = l == 0 ? b0 : (l == 1 ? b1 : b2);
        const float* sp   = l == 0 ? p0 : (l == 1 ? p1 : p2);
        wt_core(coef, sb, sp, Wt + (size_t)l * O_DIM * KDIM, idx & 262143);
    }
    // ---- features layer 0 (524288 items = 4 iters) ----
#pragma unroll
    for (int it = 0; it < 4; ++it) {
        int idx = it * NTOT + gtid;
        features_core(x0[idx], g0, idx & (I_DIM - 1), F + (size_t)idx * KPI);
    }
    grid_barrier(bar, 0);

    int phase = 1;
    for (int l = 0; l < 3; ++l) {
        gemm_stage(F, Wt + (size_t)l * O_DIM * KDIM, P, lA, lB, blk, tid);
        grid_barrier(bar, phase++);
        if (l < 2) {
            const float* gr = (l == 0) ? g1 : g2;
#pragma unroll
            for (int it = 0; it < 4; ++it) {
                int idx = it * NTOT + gtid;
                float xv = 0.f;
#pragma unroll
                for (int s = 0; s < SPLITK; ++s)
                    xv += P[(size_t)s * (NBATCH * I_DIM) + idx];
                features_core(xv, gr, idx & (I_DIM - 1), F + (size_t)idx * KPI);
            }
            grid_barrier(bar, phase++);
        }
    }

    // ---- final splitK reduce -> out ----
#pragma unroll
    for (int it = 0; it < 4; ++it) {
        int idx = it * NTOT + gtid;
        float v = 0.f;
#pragma unroll
        for (int s = 0; s < SPLITK; ++s)
            v += P[(size_t)s * (NBATCH * O_DIM) + idx];
        out[idx] = v;
    }
}

// ---------------------------------------------------------------------------
extern "C" void kernel_launch(void* const* d_in, const int* in_sizes, int n_in,
                              void* d_out, int out_size, void* d_ws, size_t ws_size,
                              hipStream_t stream) {
    const float* x0 = (const float*)d_in[0];
    const float* g0 = (const float*)d_in[1];
    const float* c0 = (const float*)d_in[2];
    const float* b0 = (const float*)d_in[3];
    const float* p0 = (const float*)d_in[4];
    const float* g1 = (const float*)d_in[5];
    const float* c1 = (const float*)d_in[6];
    const float* b1 = (const float*)d_in[7];
    const float* p1 = (const float*)d_in[8];
    const float* g2 = (const float*)d_in[9];
    const float* c2 = (const float*)d_in[10];
    const float* b2 = (const float*)d_in[11];
    const float* p2 = (const float*)d_in[12];

    char* ws = (char*)d_ws;
    const size_t wt_bytes = (size_t)O_DIM * KDIM * sizeof(__hip_bfloat16);   // 6.3 MB/layer
    const size_t f_bytes  = (size_t)NBATCH * KDIM * sizeof(__hip_bfloat16);  // 12.6 MB
    __hip_bfloat16* Wt = (__hip_bfloat16*)ws;
    __hip_bfloat16* F  = (__hip_bfloat16*)(ws + 3 * wt_bytes);
    float* P  = (float*)(ws + 3 * wt_bytes + f_bytes);   // [16][1024][512] fp32 = 33.6 MB
    int* bar  = (int*)(ws + (size_t)128 * 1024 * 1024);  // barrier counters, far from data
    float* out = (float*)d_out;

    // zero the 6 one-shot barrier counters; capture-legal memset node
    hipMemsetAsync(bar, 0, 4096, stream);

    fused_kan<<<NBLK, NTHR, 0, stream>>>(
        x0, g0, c0, b0, p0, g1, c1, b1, p1, g2, c2, b2, p2,
        Wt, F, P, bar, out);
}

// Round 7
// 205.151 us; speedup vs baseline: 4.0652x; 2.9613x over previous
//
#include <hip/hip_runtime.h>
#include <hip/hip_bf16.h>

#define I_DIM  512
#define O_DIM  512
#define NBATCH 1024
#define NSPL   8            // spline coeffs per input channel
#define KPI    12           // K slots per channel: 8 spline + s_hi,s_hi,s_lo,0
#define KDIM   (I_DIM * KPI)   // 6144
#define NGRID  12           // extended grid points per channel
#define SPLITK 8

typedef __attribute__((ext_vector_type(8))) short bf16x8;
typedef __attribute__((ext_vector_type(4))) float f32x4;

// async global->LDS 16B: per-lane source, wave-uniform LDS base (+lane*16 in HW)
__device__ __forceinline__ void gload_lds16(const __hip_bfloat16* g, __hip_bfloat16* l) {
    __builtin_amdgcn_global_load_lds(
        (const __attribute__((address_space(1))) void*)g,
        (__attribute__((address_space(3))) void*)l, 16, 0, 0);
}

// ---------------------------------------------------------------------------
// Wt row: slots 0..7 = sp*coef[k]; 8=hi(sb); 9=lo(sb); 10=hi(sb); 11=0.
// Pairs with features [B0..B7, s_hi, s_hi, s_lo, 0]:
//   s_hi*w_hi + s_hi*w_lo + s_lo*w_hi ~= s*sb  (rel err ~2^-17; verified r1-r6)
// ---------------------------------------------------------------------------
__device__ __forceinline__ void wt_core(const float* __restrict__ coef,
                                        const float* __restrict__ sb,
                                        const float* __restrict__ sp,
                                        __hip_bfloat16* __restrict__ W, int tid) {
    int i = tid & (I_DIM - 1);
    int o = tid >> 9;
    float sbv = sb[i * O_DIM + o];
    float spv = sp[i * O_DIM + o];
    const float* cf = coef + (size_t)(i * O_DIM + o) * NSPL;
    __align__(16) __hip_bfloat16 row[KPI];
#pragma unroll
    for (int k = 0; k < NSPL; ++k) row[k] = __float2bfloat16(spv * cf[k]);
    __hip_bfloat16 whi = __float2bfloat16(sbv);
    __hip_bfloat16 wlo = __float2bfloat16(sbv - __bfloat162float(whi));
    row[8]  = whi;
    row[9]  = wlo;
    row[10] = whi;
    row[11] = __float2bfloat16(0.0f);
    uint2* dst = (uint2*)(W + (size_t)o * KDIM + i * KPI);
    const uint2* src = (const uint2*)row;
    dst[0] = src[0]; dst[1] = src[1]; dst[2] = src[2];
}

__device__ __forceinline__ void features_core(float xv, const float* __restrict__ grid,
                                              int i, __hip_bfloat16* __restrict__ dst) {
    float g[NGRID];
#pragma unroll
    for (int j = 0; j < NGRID; ++j) g[j] = grid[i * NGRID + j];

    float B[NGRID - 1];
#pragma unroll
    for (int j = 0; j < NGRID - 1; ++j)
        B[j] = (xv >= g[j] && xv < g[j + 1]) ? 1.0f : 0.0f;
#pragma unroll
    for (int p = 1; p <= 3; ++p) {
#pragma unroll
        for (int j = 0; j < NGRID - 1 - p; ++j) {
            B[j] = (xv - g[j]) / (g[j + p] - g[j]) * B[j]
                 + (g[j + p + 1] - xv) / (g[j + p + 1] - g[j + 1]) * B[j + 1];
        }
    }
    float s = xv / (1.0f + __expf(-xv));  // silu
    __hip_bfloat16 shi = __float2bfloat16(s);
    __hip_bfloat16 slo = __float2bfloat16(s - __bfloat162float(shi));

    __align__(16) __hip_bfloat16 row[KPI];
#pragma unroll
    for (int k = 0; k < NSPL; ++k) row[k] = __float2bfloat16(B[k]);
    row[8]  = shi;
    row[9]  = shi;
    row[10] = slo;
    row[11] = __float2bfloat16(0.0f);

    uint2* d = (uint2*)dst;
    const uint2* srow = (const uint2*)row;
    d[0] = srow[0]; d[1] = srow[1]; d[2] = srow[2];
}

// ---------------------------------------------------------------------------
// Fused prep (r3-verified): blocks [0,3072) build Wt (3 layers); [3072,5120)
// build layer-0 features from x.
// ---------------------------------------------------------------------------
__global__ void prep_kernel(const float* __restrict__ c0, const float* __restrict__ b0, const float* __restrict__ p0,
                            const float* __restrict__ c1, const float* __restrict__ b1, const float* __restrict__ p1,
                            const float* __restrict__ c2, const float* __restrict__ b2, const float* __restrict__ p2,
                            __hip_bfloat16* __restrict__ Wt,
                            const float* __restrict__ x, const float* __restrict__ grid0,
                            __hip_bfloat16* __restrict__ F) {
    if (blockIdx.x < 3072) {
        int l = blockIdx.x / 1024;
        const float* coef = l == 0 ? c0 : (l == 1 ? c1 : c2);
        const float* sb   = l == 0 ? b0 : (l == 1 ? b1 : b2);
        const float* sp   = l == 0 ? p0 : (l == 1 ? p1 : p2);
        int tid = (blockIdx.x - l * 1024) * 256 + threadIdx.x;
        wt_core(coef, sb, sp, Wt + (size_t)l * O_DIM * KDIM, tid);
    } else {
        int tid = (blockIdx.x - 3072) * 256 + threadIdx.x;
        features_core(x[tid], grid0, tid & (I_DIM - 1), F + (size_t)tid * KPI);
    }
}

// splitK-partial sum fused into next layer's feature build
__global__ void build_features_sum(const float* __restrict__ P,
                                   const float* __restrict__ grid,
                                   __hip_bfloat16* __restrict__ F) {
    int tid = blockIdx.x * blockDim.x + threadIdx.x;
    float xv = 0.f;
#pragma unroll
    for (int s = 0; s < SPLITK; ++s) xv += P[(size_t)s * (NBATCH * I_DIM) + tid];
    features_core(xv, grid, tid & (I_DIM - 1), F + (size_t)tid * KPI);
}

__global__ void reduce_out(const float* __restrict__ P, float* __restrict__ out) {
    int tid = blockIdx.x * blockDim.x + threadIdx.x;
    float v = 0.f;
#pragma unroll
    for (int s = 0; s < SPLITK; ++s) v += P[(size_t)s * (NBATCH * O_DIM) + tid];
    out[tid] = v;
}

// ---------------------------------------------------------------------------
// GEMM: P[ks][b,o] = sum_{k in seg} F[b,k]*Wt[o][k]  (bf16 MFMA, fp32 acc)
// 64x64 tile, BK=128 (6 K-rounds), 4 waves x 32x32 quadrant (2x2 MFMA x 4 kh
// = 16 MFMA/wave/round). Flat 1024-block grid, ks = blk & 7: round-robin
// block->XCD dispatch pins one K-segment per XCD -> per-XCD L2 footprint
// 1.6MB(A-seg)+0.8MB(B-seg) = 2.4MB < 4MB -> staging loads are L2 hits.
// global_load_lds w16, XOR-swizzled chunks (pos = src ^ (row&7), 16-chunk
// rows: bit3 preserved, low-3 XOR -> bank group (chunk&7)*4 spreads all 8
// groups, residual aliasing 2-way = free). 4 blocks/CU (16 waves).
// ---------------------------------------------------------------------------
#define BM 64
#define BN 64
#define BK 128                 // bf16 per row = 256 B = 16 chunks of 16 B
#define KSEG (KDIM / SPLITK)   // 768 -> 6 K-rounds

__global__ __launch_bounds__(256, 4)
void gemm_kernel(const __hip_bfloat16* __restrict__ A,   // [NBATCH][KDIM]
                 const __hip_bfloat16* __restrict__ Wt,  // [O_DIM][KDIM]
                 float* __restrict__ P) {                // [SPLITK][NBATCH][O_DIM]
    __shared__ __hip_bfloat16 lA[BM * BK];   // 16 KB
    __shared__ __hip_bfloat16 lB[BN * BK];   // 16 KB

    int blk = blockIdx.x;
    int ks = blk & 7;           // XCD-partitioned K-segment
    int t  = blk >> 3;
    int bm = t & 15;            // 0..15
    int bn = t >> 4;            // 0..7
    int tid = threadIdx.x;
    int lane = tid & 63;
    int wave = tid >> 6;
    int wr = (wave & 1) * 32;
    int wc = (wave >> 1) * 32;
    int q  = lane >> 4;
    int ln = lane & 15;

    f32x4 acc[2][2];
#pragma unroll
    for (int a = 0; a < 2; ++a)
#pragma unroll
        for (int b = 0; b < 2; ++b) acc[a][b] = (f32x4){0.f, 0.f, 0.f, 0.f};

    const __hip_bfloat16* Abase = A  + (size_t)(bm * BM) * KDIM + ks * KSEG;
    const __hip_bfloat16* Bbase = Wt + (size_t)(bn * BN) * KDIM + ks * KSEG;

    // staging: 64 rows x 16 chunks = 1024 chunks per tile; 4 calls/wave each
    // for A and B. chunk v -> row r = v>>4, pos p = v&15, source j = p^(r&7).
    int rr[4], jj[4], bb[4];
#pragma unroll
    for (int c = 0; c < 4; ++c) {
        int v = c * 256 + tid;
        rr[c] = v >> 4;
        jj[c] = (v & 15) ^ (rr[c] & 7);
        bb[c] = (c * 256 + wave * 64) * 8;   // wave-uniform LDS elem offset
    }

    for (int kt = 0; kt < KSEG; kt += BK) {
        __syncthreads();
#pragma unroll
        for (int c = 0; c < 4; ++c)
            gload_lds16(Abase + (size_t)rr[c] * KDIM + kt + jj[c] * 8, lA + bb[c]);
#pragma unroll
        for (int c = 0; c < 4; ++c)
            gload_lds16(Bbase + (size_t)rr[c] * KDIM + kt + jj[c] * 8, lB + bb[c]);
        __syncthreads();

#pragma unroll
        for (int kh = 0; kh < 4; ++kh) {
            bf16x8 af[2], bf[2];
#pragma unroll
            for (int rt = 0; rt < 2; ++rt) {
                int row = wr + rt * 16 + ln;
                af[rt] = *(const bf16x8*)(lA + row * BK + (((kh * 4 + q) ^ (row & 7)) * 8));
            }
#pragma unroll
            for (int ct = 0; ct < 2; ++ct) {
                int row = wc + ct * 16 + ln;
                bf[ct] = *(const bf16x8*)(lB + row * BK + (((kh * 4 + q) ^ (row & 7)) * 8));
            }
#pragma unroll
            for (int rt = 0; rt < 2; ++rt)
#pragma unroll
                for (int ct = 0; ct < 2; ++ct)
                    acc[rt][ct] = __builtin_amdgcn_mfma_f32_16x16x32_bf16(
                        af[rt], bf[ct], acc[rt][ct], 0, 0, 0);
        }
    }

    // epilogue: C/D layout col = lane&15, row = quad*4 + reg (verified r1-r6)
    float* Pp = P + (size_t)ks * NBATCH * O_DIM;
    int orow = bm * BM + wr;
    int ocol = bn * BN + wc + ln;
#pragma unroll
    for (int rt = 0; rt < 2; ++rt)
#pragma unroll
        for (int ct = 0; ct < 2; ++ct)
#pragma unroll
            for (int r = 0; r < 4; ++r)
                Pp[(size_t)(orow + rt * 16 + q * 4 + r) * O_DIM + ocol + ct * 16]
                    = acc[rt][ct][r];
}

// ---------------------------------------------------------------------------
extern "C" void kernel_launch(void* const* d_in, const int* in_sizes, int n_in,
                              void* d_out, int out_size, void* d_ws, size_t ws_size,
                              hipStream_t stream) {
    const float* x0      = (const float*)d_in[0];
    const float* grid[3] = {(const float*)d_in[1], (const float*)d_in[5], (const float*)d_in[9]};
    const float* coef[3] = {(const float*)d_in[2], (const float*)d_in[6], (const float*)d_in[10]};
    const float* sb[3]   = {(const float*)d_in[3], (const float*)d_in[7], (const float*)d_in[11]};
    const float* sp[3]   = {(const float*)d_in[4], (const float*)d_in[8], (const float*)d_in[12]};

    char* ws = (char*)d_ws;
    const size_t wt_bytes = (size_t)O_DIM * KDIM * sizeof(__hip_bfloat16);   // 6.3 MB/layer
    const size_t f_bytes  = (size_t)NBATCH * KDIM * sizeof(__hip_bfloat16);  // 12.6 MB
    __hip_bfloat16* Wt = (__hip_bfloat16*)ws;
    __hip_bfloat16* F  = (__hip_bfloat16*)(ws + 3 * wt_bytes);
    float* P = (float*)(ws + 3 * wt_bytes + f_bytes);   // [8][1024][512] fp32 = 16.8 MB

    prep_kernel<<<5120, 256, 0, stream>>>(
        coef[0], sb[0], sp[0], coef[1], sb[1], sp[1], coef[2], sb[2], sp[2],
        Wt, x0, grid[0], F);
    gemm_kernel<<<1024, 256, 0, stream>>>(F, Wt, P);

    for (int l = 1; l < 3; ++l) {
        build_features_sum<<<(NBATCH * I_DIM) / 256, 256, 0, stream>>>(P, grid[l], F);
        gemm_kernel<<<1024, 256, 0, stream>>>(F, Wt + (size_t)l * O_DIM * KDIM, P);
    }
    reduce_out<<<(NBATCH * O_DIM) / 256, 256, 0, stream>>>(P, (float*)d_out);
}